// Round 4
// baseline (666.263 us; speedup 1.0000x reference)
//
#include <hip/hip_runtime.h>
#include <math.h>

// Problem constants
#define BATCH 256
#define IC    1152   // 32*6*6 input capsule positions
#define DD    8
#define OO    10
#define EE    16
#define BPW   6      // batches per wave: lane = b_loc*10 + o (lanes 60..63 idle)
#define WPB   4      // waves per block (256 threads)
#define BPB   (BPW * WPB)   // 24 batches per block
#define NBB   11     // ceil(256/24) batch-groups
#define NT    256
#define CHUNK 9      // ijk per block
#define NCHUNK 128   // IC / CHUNK

// pass kernel, wave-autonomous form:
//  - lane = b_loc*10 + o  -> all 10 output caps of a batch live in ONE wave.
//    Softmax over o = 10 ds_bpermute gathers. NO LDS, NO barriers, no
//    inter-wave coupling; every wave runs free -> latency hiding works.
//  - W via per-lane float4 vector loads (vmcnt-tracked, pipelined). 6 lanes
//    share each address (same o) -> coalescer merges; 4 waves/block share the
//    same W chunk -> L1/L2 reuse. No SGPR pressure, no smem/ds lgkm tangle.
//  - NO launch_bounds occupancy demand: compiler allocates ~80-96 VGPR for
//    the u[16]+sacc[16]+vreg[16]+xr[8] live set WITHOUT spilling
//    (check: WRITE_SIZE must be ~21 MB = s_part only).
//  - grid = 128 chunks x 11 batch-groups = 1408 blocks of 4 waves
//    (~5.5 blocks/CU, nearly all resident).
__global__ __launch_bounds__(NT) void caps_pass_kernel(
    const float* __restrict__ x,       // [256][1152][8]
    const float* __restrict__ W,       // [1152][10][8][16]
    const float* __restrict__ V,       // [256][10][16] accumulated v
    float* __restrict__ s_part,        // [NCHUNK][256][10][16]
    int first)
{
    const int tid   = threadIdx.x;
    const int wv    = tid >> 6;
    const int lane  = tid & 63;
    const int bloc  = lane / 10;          // 0..6 (6 => idle lane)
    const int o     = lane - bloc * 10;   // 0..9
    const int gbase = lane - o;           // first lane of my 10-lane o-group
    const int b0    = blockIdx.y * BPB + wv * BPW;
    const bool bval = (bloc < BPW) && (b0 + bloc < BATCH);
    const int b     = bval ? (b0 + bloc) : (BATCH - 1);  // clamped, safe loads
    const int ijk0  = blockIdx.x * CHUNK;

    const float* xb = x + (size_t)b * (IC * DD);

    // per-lane copy of V[b,o,:] (perfectly coalesced: lane -> (b*10+o)*64B)
    float vreg[EE];
    if (!first) {
        const float4* vp = reinterpret_cast<const float4*>(V + ((size_t)b * OO + o) * EE);
        #pragma unroll
        for (int q = 0; q < 4; ++q) {
            float4 t = vp[q];
            vreg[q * 4 + 0] = t.x; vreg[q * 4 + 1] = t.y;
            vreg[q * 4 + 2] = t.z; vreg[q * 4 + 3] = t.w;
        }
    }

    float sacc[EE];
    #pragma unroll
    for (int e = 0; e < EE; ++e) sacc[e] = 0.f;

    #pragma unroll 1
    for (int r = 0; r < CHUNK; ++r) {
        const int ijk = ijk0 + r;

        // x[b][ijk][0:8]: 32 B per lane; 10 lanes share each address
        const float4 x0 = *reinterpret_cast<const float4*>(xb + (size_t)ijk * DD);
        const float4 x1 = *reinterpret_cast<const float4*>(xb + (size_t)ijk * DD + 4);
        float xr[DD];
        xr[0] = x0.x; xr[1] = x0.y; xr[2] = x0.z; xr[3] = x0.w;
        xr[4] = x1.x; xr[5] = x1.y; xr[6] = x1.z; xr[7] = x1.w;

        // u[e] = sum_d x_d * W[ijk][o][d][e]   (W via vector float4 loads)
        const float* wp = W + (size_t)ijk * (OO * DD * EE) + o * (DD * EE);
        float u[EE];
        #pragma unroll
        for (int e = 0; e < EE; ++e) u[e] = 0.f;
        #pragma unroll
        for (int d = 0; d < DD; ++d) {
            const float4* wd = reinterpret_cast<const float4*>(wp + d * EE);
            #pragma unroll
            for (int q = 0; q < 4; ++q) {
                const float4 w4 = wd[q];
                u[q * 4 + 0] = fmaf(xr[d], w4.x, u[q * 4 + 0]);
                u[q * 4 + 1] = fmaf(xr[d], w4.y, u[q * 4 + 1]);
                u[q * 4 + 2] = fmaf(xr[d], w4.z, u[q * 4 + 2]);
                u[q * 4 + 3] = fmaf(xr[d], w4.w, u[q * 4 + 3]);
            }
        }

        if (!first) {
            // logit, then softmax over the 10 o-lanes of my b-group (bounded
            // logits -> no max subtraction), all via cross-lane gathers
            float lg = 0.f;
            #pragma unroll
            for (int e = 0; e < EE; ++e) lg = fmaf(u[e], vreg[e], lg);
            const float elg = __expf(lg);
            float den = 0.f;
            #pragma unroll
            for (int oo = 0; oo < OO; ++oo)
                den += __shfl(elg, gbase + oo, 64);
            const float c = __fdividef(elg, den);
            #pragma unroll
            for (int e = 0; e < EE; ++e) sacc[e] = fmaf(c, u[e], sacc[e]);
        } else {
            #pragma unroll
            for (int e = 0; e < EE; ++e) sacc[e] += u[e];
        }
    }

    // write partial s for this chunk (first pass: c = 0.1 uniform, folded here)
    if (bval) {
        const float mul = first ? 0.1f : 1.0f;
        float* sp = s_part + (((size_t)blockIdx.x * BATCH + b) * OO + o) * EE;
        #pragma unroll
        for (int q = 0; q < 4; ++q) {
            float4 t;
            t.x = mul * sacc[q * 4 + 0]; t.y = mul * sacc[q * 4 + 1];
            t.z = mul * sacc[q * 4 + 2]; t.w = mul * sacc[q * 4 + 3];
            reinterpret_cast<float4*>(sp)[q] = t;
        }
    }
}

// squash kernel: reduce partial s over chunks, squash, update V (or write out).
// 4 waves/block split the 128-chunk reduction 4-way (32 chunks each), then
// LDS-reduce; wave 0 does the squash + store. 640 blocks keep it BW-bound.
__global__ __launch_bounds__(256) void caps_squash_kernel(
    const float* __restrict__ s_part,  // [NCHUNK][256][10][16]
    float* __restrict__ V,             // [256][10][16]
    float* __restrict__ out,           // [256][10][16]
    int accum, int last)
{
    __shared__ float red[3][64];
    const int lane = threadIdx.x & 63;
    const int w    = threadIdx.x >> 6;
    const int g    = blockIdx.x * 64 + lane;    // < 40960

    const float* sp = s_part + g;
    float s = 0.f;
    #pragma unroll 8
    for (int ch = w * (NCHUNK / 4); ch < (w + 1) * (NCHUNK / 4); ++ch)
        s += sp[(size_t)ch * (BATCH * OO * EE)];

    if (w > 0) red[w - 1][lane] = s;
    __syncthreads();
    if (w == 0) {
        s += red[0][lane] + red[1][lane] + red[2][lane];

        // squared norm over the 16-element e axis (lanes g..g+15 share (b,o))
        float sq = s * s;
        #pragma unroll
        for (int m = 1; m < 16; m <<= 1) sq += __shfl_xor(sq, m, 16);

        float scale = sq / (1.f + sq) / (sqrtf(sq) + 1e-6f);
        float v = scale * s;

        if (last)       out[g] = v;
        else if (accum) V[g]  += v;
        else            V[g]   = v;
    }
}

extern "C" void kernel_launch(void* const* d_in, const int* in_sizes, int n_in,
                              void* d_out, int out_size, void* d_ws, size_t ws_size,
                              hipStream_t stream) {
    const float* x = (const float*)d_in[0];   // [256,32,6,6,8]
    const float* W = (const float*)d_in[1];   // [1,32,6,6,10,8,16]
    float* out = (float*)d_out;               // [256,10,16]

    float* s_part = (float*)d_ws;                                   // NCHUNK*40960 floats
    float* V      = s_part + (size_t)NCHUNK * BATCH * OO * EE;      // 40960 floats

    dim3 grid(NCHUNK, NBB), blk(NT);
    const int sq_blocks = (BATCH * OO * EE) / 64;   // 640

    // iteration 1: b=0 -> c uniform 0.1; v1 -> V
    caps_pass_kernel<<<grid, blk, 0, stream>>>(x, W, V, s_part, 1);
    caps_squash_kernel<<<sq_blocks, 256, 0, stream>>>(s_part, V, out, 0, 0);
    // iteration 2: logits = dot(u_hat, v1); V += v2
    caps_pass_kernel<<<grid, blk, 0, stream>>>(x, W, V, s_part, 0);
    caps_squash_kernel<<<sq_blocks, 256, 0, stream>>>(s_part, V, out, 1, 0);
    // iteration 3 (final): logits = dot(u_hat, v1+v2); output v3
    caps_pass_kernel<<<grid, blk, 0, stream>>>(x, W, V, s_part, 0);
    caps_squash_kernel<<<sq_blocks, 256, 0, stream>>>(s_part, V, out, 0, 1);
}

// Round 5
// 251.917 us; speedup vs baseline: 2.6448x; 2.6448x over previous
//
#include <hip/hip_runtime.h>
#include <math.h>

// Problem constants
#define BATCH 256
#define IC    1152   // 32*6*6 input capsule positions
#define DD    8
#define OO    10
#define EE    16
#define BTILE 64     // batches per block (one wave per o, lanes = batch)
#define NBT   4      // BATCH / BTILE
#define NT    640    // OO * BTILE threads per block (10 waves)
#define CHUNK 9      // ijk positions per block
#define NCHUNK 128   // IC / CHUNK  -> 512 blocks = 2 blocks/CU (if VGPR<=102)
#define ROUNDS CHUNK // SJ = 1: one ijk per round, u[16] live across barrier

// pass kernel (round-0 structure, register-safe):
//  - W consumed from SGPRs: o is wave-uniform (readfirstlane) -> s_load
//    dwordx16 bursts; proven the fastest W path (46 us/pass at 2.5 w/SIMD).
//  - x double-buffered in LDS (coalesced loader, register prefetch 1 round).
//  - SJ=1: only u[16] (+sacc[16]+vreg[16]) live across the barrier.
//  - NO launch_bounds occupancy demand. Evidence r1-r4: any min-waves cap
//    makes the allocator pick 32-48 VGPR and spill ~25-57 MB to scratch;
//    uncapped it picks ~60-90 for this live set with ZERO spill, which is
//    <=102 -> two 640-thread blocks co-resident (20 waves/CU, 2x round 0).
//    (check: VGPR_Count 70-102, WRITE_SIZE ~21 MB)
//  - softmax exchanges exp(logit) via LDS; logits bounded -> no max-sub
//    (verified passing, absmax unchanged, rounds 1-4).
__global__ __launch_bounds__(NT) void caps_pass_kernel(
    const float* __restrict__ x,       // [256][1152][8]
    const float* __restrict__ W,       // [1152][10][8][16]
    const float* __restrict__ V,       // [256][10][16] accumulated v
    float* __restrict__ s_part,        // [NCHUNK][256][10][16]
    int first)
{
    __shared__ float x_lds[2][DD][BTILE];   // d-major: conflict-free b32 reads
    __shared__ float elg_lds[2][NT];

    const int tid = threadIdx.x;
    const int o   = tid >> 6;        // wave id 0..9
    const int bl  = tid & 63;
    const int o_u = __builtin_amdgcn_readfirstlane(o);   // wave-uniform o
    const int b   = blockIdx.y * BTILE + bl;
    const int ijk0 = blockIdx.x * CHUNK;

    // per-thread copy of V[b,o,:] (only needed when routing is active)
    float vreg[EE];
    if (!first) {
        const float4* vp = reinterpret_cast<const float4*>(V + ((size_t)b * OO + o) * EE);
        #pragma unroll
        for (int q = 0; q < 4; ++q) {
            float4 t = vp[q];
            vreg[q * 4 + 0] = t.x; vreg[q * 4 + 1] = t.y;
            vreg[q * 4 + 2] = t.z; vreg[q * 4 + 3] = t.w;
        }
    }

    float sacc[EE];
    #pragma unroll
    for (int e = 0; e < EE; ++e) sacc[e] = 0.f;

    // x loader mapping: threads 0..127 each fetch one float4 per round
    const bool loader = tid < BTILE * 2;   // 128
    const int lb = (tid >> 1) & 63;        // batch within tile
    const int lq = tid & 1;                // which half of the 8 d's
    const float* xbase = x + (size_t)(blockIdx.y * BTILE + lb) * (IC * DD) + lq * 4;

    // prologue: load round 0, write to buffer 0
    float4 xpre = make_float4(0.f, 0.f, 0.f, 0.f);
    if (loader) {
        xpre = *reinterpret_cast<const float4*>(xbase + (size_t)ijk0 * DD);
        x_lds[0][lq * 4 + 0][lb] = xpre.x;
        x_lds[0][lq * 4 + 1][lb] = xpre.y;
        x_lds[0][lq * 4 + 2][lb] = xpre.z;
        x_lds[0][lq * 4 + 3][lb] = xpre.w;
    }
    __syncthreads();

    int p = 0;
    #pragma unroll 1
    for (int r = 0; r < ROUNDS; ++r) {
        // issue global prefetch for round r+1 (latency hidden by compute)
        if (r + 1 < ROUNDS && loader)
            xpre = *reinterpret_cast<const float4*>(
                xbase + (size_t)(ijk0 + r + 1) * DD);

        // compute u for this ijk; write exp(logit)
        const int ijk = ijk0 + r;
        const float* wp = W + (size_t)ijk * (OO * DD * EE) + o_u * (DD * EE);
        float xr[DD];
        #pragma unroll
        for (int d = 0; d < DD; ++d) xr[d] = x_lds[p][d][bl];
        float u[EE];
        #pragma unroll
        for (int e = 0; e < EE; ++e) u[e] = 0.f;
        #pragma unroll
        for (int d = 0; d < DD; ++d) {
            #pragma unroll
            for (int e = 0; e < EE; ++e)
                u[e] = fmaf(xr[d], wp[d * EE + e], u[e]);  // W from SGPR
        }
        float elg = 0.f;
        if (!first) {
            float lg = 0.f;
            #pragma unroll
            for (int e = 0; e < EE; ++e) lg = fmaf(u[e], vreg[e], lg);
            // logits bounded: softmax without max-subtraction
            elg = __expf(lg);
            elg_lds[p][tid] = elg;
        }

        // write prefetched x into the other buffer
        if (r + 1 < ROUNDS && loader) {
            x_lds[p ^ 1][lq * 4 + 0][lb] = xpre.x;
            x_lds[p ^ 1][lq * 4 + 1][lb] = xpre.y;
            x_lds[p ^ 1][lq * 4 + 2][lb] = xpre.z;
            x_lds[p ^ 1][lq * 4 + 3][lb] = xpre.w;
        }

        // single barrier per round (covers x swap + elg visibility)
        __syncthreads();

        // softmax over o, accumulate s
        if (!first) {
            float den = 0.f;
            #pragma unroll
            for (int oo = 0; oo < OO; ++oo)
                den += elg_lds[p][oo * 64 + bl];
            float c = __fdividef(elg, den);
            #pragma unroll
            for (int e = 0; e < EE; ++e)
                sacc[e] = fmaf(c, u[e], sacc[e]);
        } else {
            #pragma unroll
            for (int e = 0; e < EE; ++e) sacc[e] += u[e];
        }
        p ^= 1;
    }

    // write partial s for this chunk (first pass: c = 0.1 uniform, folded here)
    const float mul = first ? 0.1f : 1.0f;
    float* sp = s_part + (((size_t)blockIdx.x * BATCH + b) * OO + o) * EE;
    #pragma unroll
    for (int q = 0; q < 4; ++q) {
        float4 t;
        t.x = mul * sacc[q * 4 + 0]; t.y = mul * sacc[q * 4 + 1];
        t.z = mul * sacc[q * 4 + 2]; t.w = mul * sacc[q * 4 + 3];
        reinterpret_cast<float4*>(sp)[q] = t;
    }
}

// squash kernel: reduce partial s over chunks, squash, update V (or write out).
// 4 waves/block split the 128-chunk reduction 4-way (32 chunks each), then
// LDS-reduce; wave 0 does the squash + store. 640 blocks keep it BW-bound.
__global__ __launch_bounds__(256) void caps_squash_kernel(
    const float* __restrict__ s_part,  // [NCHUNK][256][10][16]
    float* __restrict__ V,             // [256][10][16]
    float* __restrict__ out,           // [256][10][16]
    int accum, int last)
{
    __shared__ float red[3][64];
    const int lane = threadIdx.x & 63;
    const int w    = threadIdx.x >> 6;
    const int g    = blockIdx.x * 64 + lane;    // < 40960

    const float* sp = s_part + g;
    float s = 0.f;
    #pragma unroll 8
    for (int ch = w * (NCHUNK / 4); ch < (w + 1) * (NCHUNK / 4); ++ch)
        s += sp[(size_t)ch * (BATCH * OO * EE)];

    if (w > 0) red[w - 1][lane] = s;
    __syncthreads();
    if (w == 0) {
        s += red[0][lane] + red[1][lane] + red[2][lane];

        // squared norm over the 16-element e axis (lanes g..g+15 share (b,o))
        float sq = s * s;
        #pragma unroll
        for (int m = 1; m < 16; m <<= 1) sq += __shfl_xor(sq, m, 16);

        float scale = sq / (1.f + sq) / (sqrtf(sq) + 1e-6f);
        float v = scale * s;

        if (last)       out[g] = v;
        else if (accum) V[g]  += v;
        else            V[g]   = v;
    }
}

extern "C" void kernel_launch(void* const* d_in, const int* in_sizes, int n_in,
                              void* d_out, int out_size, void* d_ws, size_t ws_size,
                              hipStream_t stream) {
    const float* x = (const float*)d_in[0];   // [256,32,6,6,8]
    const float* W = (const float*)d_in[1];   // [1,32,6,6,10,8,16]
    float* out = (float*)d_out;               // [256,10,16]

    float* s_part = (float*)d_ws;                                   // NCHUNK*40960 floats
    float* V      = s_part + (size_t)NCHUNK * BATCH * OO * EE;      // 40960 floats

    dim3 grid(NCHUNK, NBT), blk(NT);
    const int sq_blocks = (BATCH * OO * EE) / 64;   // 640

    // iteration 1: b=0 -> c uniform 0.1; v1 -> V
    caps_pass_kernel<<<grid, blk, 0, stream>>>(x, W, V, s_part, 1);
    caps_squash_kernel<<<sq_blocks, 256, 0, stream>>>(s_part, V, out, 0, 0);
    // iteration 2: logits = dot(u_hat, v1); V += v2
    caps_pass_kernel<<<grid, blk, 0, stream>>>(x, W, V, s_part, 0);
    caps_squash_kernel<<<sq_blocks, 256, 0, stream>>>(s_part, V, out, 1, 0);
    // iteration 3 (final): logits = dot(u_hat, v1+v2); output v3
    caps_pass_kernel<<<grid, blk, 0, stream>>>(x, W, V, s_part, 0);
    caps_squash_kernel<<<sq_blocks, 256, 0, stream>>>(s_part, V, out, 0, 1);
}

// Round 6
// 158.578 us; speedup vs baseline: 4.2015x; 1.5886x over previous
//
#include <hip/hip_runtime.h>
#include <math.h>

// Problem constants
#define BATCH 256
#define IC    1152   // 32*6*6 input capsule positions
#define DD    8
#define OO    10
#define EE    16
#define BTILE 64     // batches per block (one wave per o, lanes = batch)
#define NBT   4      // BATCH / BTILE
#define NT    640    // OO * BTILE threads per block (10 waves)
#define CHUNK 9      // ijk positions per block
#define NCHUNK 128   // IC / CHUNK  -> 512 blocks

// pass kernel, two-phase / two-barrier form:
//  - Stage: all 9 ijk x-tiles -> LDS (18.4 KB), one barrier.
//  - Phase A (routing only): per ijk, logit WITHOUT storing u:
//      lg = sum_d x_d * (sum_e W[d][e]*v[e])     (round-3 fold, proven)
//    write exp(lg) to elg_lds[9][640]; ONE barrier.
//  - Phase B: per ijk, den = sum_o elg (10 conflict-free ds_reads),
//    sacc[e] += sum_d (c*x_d)*W[d][e].  ZERO barriers.
//  Live sets: A = vreg[16]+xr[8], B = sacc[16]+xr[8] -- disjoint phases, so
//  uncapped alloc should land <=64 VGPR (tier boundary, m69: waves/SIMD
//  halves above 64) -> 2-3 blocks/CU resident; between barriers all waves
//  run free so the wave-uniform W s_load latency hides via TLP.
//  - W stays on the SGPR/s_load path (o wave-uniform via readfirstlane) --
//    rounds 1-4 proved per-lane VMEM W is 3-4x worse.
//  - NO launch_bounds min-waves cap (r1-r3: caps force 32-48 VGPR + 25-57 MB
//    scratch spill). Check: VGPR<=64, WRITE_SIZE ~21 MB.
__global__ __launch_bounds__(NT) void caps_pass_kernel(
    const float* __restrict__ x,       // [256][1152][8]
    const float* __restrict__ W,       // [1152][10][8][16]
    const float* __restrict__ V,       // [256][10][16] accumulated v
    float* __restrict__ s_part,        // [NCHUNK][256][10][16]
    int first)
{
    __shared__ float x_lds[CHUNK][DD][BTILE];   // d-major: conflict-free reads
    __shared__ float elg_lds[CHUNK][NT];

    const int tid = threadIdx.x;
    const int o   = tid >> 6;        // wave id 0..9
    const int bl  = tid & 63;
    const int o_u = __builtin_amdgcn_readfirstlane(o);   // wave-uniform o
    const int b   = blockIdx.y * BTILE + bl;
    const int ijk0 = blockIdx.x * CHUNK;

    // ---- stage: all CHUNK ijk x-tiles into LDS (coalesced float4) ----
    {
        const float* xgrp = x + (size_t)(blockIdx.y * BTILE) * (IC * DD);
        #pragma unroll 1
        for (int i = tid; i < CHUNK * BTILE * 2; i += NT) {
            const int lq = i & 1;            // which half of the 8 d's
            const int lb = (i >> 1) & 63;    // batch within tile
            const int ls = i >> 7;           // ijk within chunk
            const float4 t = *reinterpret_cast<const float4*>(
                xgrp + (size_t)lb * (IC * DD) + (size_t)(ijk0 + ls) * DD + lq * 4);
            x_lds[ls][lq * 4 + 0][lb] = t.x;
            x_lds[ls][lq * 4 + 1][lb] = t.y;
            x_lds[ls][lq * 4 + 2][lb] = t.z;
            x_lds[ls][lq * 4 + 3][lb] = t.w;
        }
    }
    __syncthreads();

    // ---- phase A (routing passes only): logits -> elg_lds ----
    if (!first) {
        // per-thread copy of V[b,o,:] (dead after phase A)
        float vreg[EE];
        const float4* vp = reinterpret_cast<const float4*>(V + ((size_t)b * OO + o) * EE);
        #pragma unroll
        for (int q = 0; q < 4; ++q) {
            float4 t = vp[q];
            vreg[q * 4 + 0] = t.x; vreg[q * 4 + 1] = t.y;
            vreg[q * 4 + 2] = t.z; vreg[q * 4 + 3] = t.w;
        }

        #pragma unroll 1
        for (int s = 0; s < CHUNK; ++s) {
            const float* wp = W + (size_t)(ijk0 + s) * (OO * DD * EE) + o_u * (DD * EE);
            float xr[DD];
            #pragma unroll
            for (int d = 0; d < DD; ++d) xr[d] = x_lds[s][d][bl];
            float lg = 0.f;
            #pragma unroll
            for (int d = 0; d < DD; ++d) {
                float t = 0.f;
                #pragma unroll
                for (int e = 0; e < EE; ++e)
                    t = fmaf(wp[d * EE + e], vreg[e], t);   // W from SGPR
                lg = fmaf(xr[d], t, lg);
            }
            // logits bounded -> softmax without max subtraction (proven r1-r5)
            elg_lds[s][tid] = __expf(lg);
        }
        __syncthreads();
    }

    // ---- phase B: softmax weights + accumulate (no barriers) ----
    float sacc[EE];
    #pragma unroll
    for (int e = 0; e < EE; ++e) sacc[e] = 0.f;

    #pragma unroll 1
    for (int s = 0; s < CHUNK; ++s) {
        const float* wp = W + (size_t)(ijk0 + s) * (OO * DD * EE) + o_u * (DD * EE);
        float xr[DD];
        #pragma unroll
        for (int d = 0; d < DD; ++d) xr[d] = x_lds[s][d][bl];

        float c;
        if (!first) {
            float den = 0.f;
            #pragma unroll
            for (int oo = 0; oo < OO; ++oo)
                den += elg_lds[s][oo * 64 + bl];    // bank: bl%32, 2-way free
            c = __fdividef(elg_lds[s][o * 64 + bl], den);
        } else {
            c = 1.0f;   // uniform 0.1 folded into output mul
        }

        #pragma unroll
        for (int d = 0; d < DD; ++d) {
            const float cx = c * xr[d];
            #pragma unroll
            for (int e = 0; e < EE; ++e)
                sacc[e] = fmaf(cx, wp[d * EE + e], sacc[e]);  // W from SGPR
        }
    }

    // write partial s for this chunk (first pass: c = 0.1 uniform, folded here)
    const float mul = first ? 0.1f : 1.0f;
    float* sp = s_part + (((size_t)blockIdx.x * BATCH + b) * OO + o) * EE;
    #pragma unroll
    for (int q = 0; q < 4; ++q) {
        float4 t;
        t.x = mul * sacc[q * 4 + 0]; t.y = mul * sacc[q * 4 + 1];
        t.z = mul * sacc[q * 4 + 2]; t.w = mul * sacc[q * 4 + 3];
        reinterpret_cast<float4*>(sp)[q] = t;
    }
}

// squash kernel: reduce partial s over chunks, squash, update V (or write out).
// 4 waves/block split the 128-chunk reduction 4-way (32 chunks each), then
// LDS-reduce; wave 0 does the squash + store. 640 blocks keep it BW-bound.
__global__ __launch_bounds__(256) void caps_squash_kernel(
    const float* __restrict__ s_part,  // [NCHUNK][256][10][16]
    float* __restrict__ V,             // [256][10][16]
    float* __restrict__ out,           // [256][10][16]
    int accum, int last)
{
    __shared__ float red[3][64];
    const int lane = threadIdx.x & 63;
    const int w    = threadIdx.x >> 6;
    const int g    = blockIdx.x * 64 + lane;    // < 40960

    const float* sp = s_part + g;
    float s = 0.f;
    #pragma unroll 8
    for (int ch = w * (NCHUNK / 4); ch < (w + 1) * (NCHUNK / 4); ++ch)
        s += sp[(size_t)ch * (BATCH * OO * EE)];

    if (w > 0) red[w - 1][lane] = s;
    __syncthreads();
    if (w == 0) {
        s += red[0][lane] + red[1][lane] + red[2][lane];

        // squared norm over the 16-element e axis (lanes g..g+15 share (b,o))
        float sq = s * s;
        #pragma unroll
        for (int m = 1; m < 16; m <<= 1) sq += __shfl_xor(sq, m, 16);

        float scale = sq / (1.f + sq) / (sqrtf(sq) + 1e-6f);
        float v = scale * s;

        if (last)       out[g] = v;
        else if (accum) V[g]  += v;
        else            V[g]   = v;
    }
}

extern "C" void kernel_launch(void* const* d_in, const int* in_sizes, int n_in,
                              void* d_out, int out_size, void* d_ws, size_t ws_size,
                              hipStream_t stream) {
    const float* x = (const float*)d_in[0];   // [256,32,6,6,8]
    const float* W = (const float*)d_in[1];   // [1,32,6,6,10,8,16]
    float* out = (float*)d_out;               // [256,10,16]

    float* s_part = (float*)d_ws;                                   // NCHUNK*40960 floats
    float* V      = s_part + (size_t)NCHUNK * BATCH * OO * EE;      // 40960 floats

    dim3 grid(NCHUNK, NBT), blk(NT);
    const int sq_blocks = (BATCH * OO * EE) / 64;   // 640

    // iteration 1: b=0 -> c uniform 0.1; v1 -> V
    caps_pass_kernel<<<grid, blk, 0, stream>>>(x, W, V, s_part, 1);
    caps_squash_kernel<<<sq_blocks, 256, 0, stream>>>(s_part, V, out, 0, 0);
    // iteration 2: logits = dot(u_hat, v1); V += v2
    caps_pass_kernel<<<grid, blk, 0, stream>>>(x, W, V, s_part, 0);
    caps_squash_kernel<<<sq_blocks, 256, 0, stream>>>(s_part, V, out, 1, 0);
    // iteration 3 (final): logits = dot(u_hat, v1+v2); output v3
    caps_pass_kernel<<<grid, blk, 0, stream>>>(x, W, V, s_part, 0);
    caps_squash_kernel<<<sq_blocks, 256, 0, stream>>>(s_part, V, out, 0, 1);
}